// Round 2
// baseline (309.443 us; speedup 1.0000x reference)
//
#include <hip/hip_runtime.h>
#include <hip/hip_cooperative_groups.h>
#include <math.h>

namespace cg = cooperative_groups;

#define N_ROWS 8192
#define D_DIM  512
#define C_CLS  100
#define SPLITK 16

typedef unsigned short u16;
typedef unsigned int u32;
typedef __attribute__((ext_vector_type(8))) _Float16 half8;
typedef __attribute__((ext_vector_type(4))) float floatx4;

// ---------------- ws layout (float offsets) ----------------
#define WS_G      0              // 512*512 fp32
#define WS_GP     262144         // up to 32*10*16384 fp32 splitK partials
#define WS_INV    5505024        // 8192
#define WS_WV     5513216        // 8192
#define WS_CLS    5521408        // 8192 (int)
#define WS_CNT    5529600        // 128 (int)
#define WS_U      5538048        // 100*512
#define WS_V      5589248        // 100*512
#define WS_ZTH    5640448        // 512*8192 fp16

#define LDA 517                  // P1 LDS stride

typedef const __attribute__((address_space(1))) u32* gp32;
typedef __attribute__((address_space(3))) u32* lp32;
__device__ __forceinline__ void cp16(const u16* g, u16* l) {
    __builtin_amdgcn_global_load_lds((gp32)g, (lp32)l, 16, 0, 0);
}

__device__ __forceinline__ u16 f2h(float v) {
    _Float16 h = (_Float16)v;
    return *(u16*)&h;
}

// ================= fused cooperative kernel: 5 phases, 4 grid syncs =========
__global__ __launch_bounds__(256, 3) void kFused(
        const float* __restrict__ logits, const float* __restrict__ x,
        float* __restrict__ wv, int* __restrict__ cls, float* __restrict__ inv,
        u16* __restrict__ zth, int* __restrict__ cnt, float* __restrict__ Gp,
        float* __restrict__ G, float* __restrict__ u_arr, float* __restrict__ v_arr,
        float* __restrict__ out) {
    __shared__ __attribute__((aligned(16))) union {
        struct { float xs[16 * LDA]; float ns[16]; float sv[16]; } p1;   // 33 KB
        struct { u16 Ah[2][128 * 32], Bh[2][128 * 32]; } g;              // 32 KB
        struct { float us[4][64], vs[4][64]; } uvs;
        struct { float us[8][512]; } d;                                  // 16 KB
    } sm;
    cg::grid_group grid = cg::this_grid();
    int bx = blockIdx.x, t = threadIdx.x, gdim = gridDim.x;
    int lane = t & 63, wid = t >> 6;

    // ---- P1: softmax (16 rows/block) + norm + fp16 convert/transpose ----
    if (bx == 0 && t < 128) cnt[t] = 0;
    for (int u = bx; u < 512; u += gdim) {
        __syncthreads();
        int r0 = u << 4;
        #pragma unroll
        for (int rr = 0; rr < 4; ++rr) {
            int row = r0 + (wid << 2) + rr;
            const float* lrow = logits + (size_t)row * C_CLS;
            float v1 = lrow[lane];
            bool has2 = (lane + 64) < C_CLS;
            float v2 = has2 ? lrow[lane + 64] : -INFINITY;
            float m; int idx;
            if (v2 > v1) { m = v2; idx = lane + 64; } else { m = v1; idx = lane; }
            #pragma unroll
            for (int off = 32; off >= 1; off >>= 1) {
                float om = __shfl_down(m, off);
                int   oi = __shfl_down(idx, off);
                if (om > m || (om == m && oi < idx)) { m = om; idx = oi; }
            }
            m = __shfl(m, 0); idx = __shfl(idx, 0);
            float s = expf(v1 - m) + (has2 ? expf(v2 - m) : 0.0f);
            #pragma unroll
            for (int off = 32; off >= 1; off >>= 1) s += __shfl_down(s, off);
            if (lane == 0) { wv[row] = 1.0f / s; cls[row] = idx; }
        }
        const float* src = x + (size_t)r0 * D_DIM;
        #pragma unroll
        for (int i = 0; i < 8; ++i) {
            int e = i * 1024 + t * 4;
            int r = e >> 9, c = e & 511;
            *(float4*)&sm.p1.xs[r * LDA + c] = *(const float4*)&src[e];
        }
        __syncthreads();
        {
            int r = t & 15, seg = t >> 4;
            const float* row = &sm.p1.xs[r * LDA + seg * 32];
            float ss = 0.f;
            #pragma unroll
            for (int jj = 0; jj < 32; ++jj) { float v = row[jj]; ss += v * v; }
            sm.p1.ns[r] = 0.f;
            __syncthreads();
            atomicAdd(&sm.p1.ns[r], ss);
        }
        __syncthreads();
        if (t < 16) {
            float iv = 1.0f / fmaxf(sqrtf(sm.p1.ns[t]), 1e-8f);
            inv[r0 + t] = iv;
            sm.p1.sv[t] = sqrtf(iv);
        }
        __syncthreads();
        int c = t >> 1, rq = (t & 1) * 8;
        float svl[8];
        #pragma unroll
        for (int ii = 0; ii < 8; ++ii) svl[ii] = sm.p1.sv[rq + ii];
        #pragma unroll
        for (int ct = 0; ct < 4; ++ct) {
            int d = ct * 128 + c;
            u16 o[8];
            #pragma unroll
            for (int ii = 0; ii < 8; ++ii)
                o[ii] = f2h(sm.p1.xs[(rq + ii) * LDA + d] * svl[ii]);
            uint4 val = make_uint4((u32)o[0] | ((u32)o[1] << 16),
                                   (u32)o[2] | ((u32)o[3] << 16),
                                   (u32)o[4] | ((u32)o[5] << 16),
                                   (u32)o[6] | ((u32)o[7] << 16));
            *(uint4*)&zth[(size_t)d * N_ROWS + r0 + rq] = val;
        }
    }
    grid.sync();

    // ---- P2: 160 GEMM units (splitK=16) + 800 uv units -----------------
    for (int u = bx; u < 160 + 800; u += gdim) {
        __syncthreads();
        if (u >= 160) {
            int idx = u - 160;
            int c = idx >> 3, jc = idx & 7;
            int g = wid;
            int j = jc * 64 + lane;
            float ua = 0.f, va = 0.f;
            int base = g * 2048;
            for (int b = 0; b < 2048; b += 64) {
                int mb = base + b;
                unsigned long long mask = __ballot(cls[mb + lane] == c);
                while (mask) {
                    int bit = __builtin_ctzll(mask);
                    mask &= mask - 1;
                    int m = mb + bit;
                    float wm = wv[m];
                    float wi = wm * inv[m];
                    float xv = x[(size_t)m * D_DIM + j];
                    ua += wi * xv; va += wm * xv;
                }
            }
            sm.uvs.us[g][lane] = ua; sm.uvs.vs[g][lane] = va;
            __syncthreads();
            if (g == 0) {
                u_arr[(size_t)c * D_DIM + j] = sm.uvs.us[0][lane] + sm.uvs.us[1][lane] + sm.uvs.us[2][lane] + sm.uvs.us[3][lane];
                v_arr[(size_t)c * D_DIM + j] = sm.uvs.vs[0][lane] + sm.uvs.vs[1][lane] + sm.uvs.vs[2][lane] + sm.uvs.vs[3][lane];
            }
        } else {
            int tile = u % 10;
            int p = u / 10;                 // 0..15, K-chunk of 512
            int ti = tile < 4 ? 0 : (tile < 7 ? 1 : (tile < 9 ? 2 : 3));
            int tj = tile - (ti == 0 ? 0 : (ti == 1 ? 3 : (ti == 2 ? 5 : 6)));
            int i0 = ti << 7, j0 = tj << 7;
            bool diag = (ti == tj);
            int kb = p << 9;
            int w = wid, l = lane;
            int srow = t >> 2, slot = t & 3;
            int xslot = slot ^ ((srow >> 1) & 3);     // source-side XOR swizzle
            int lm = l & 15, lg = l >> 4;
            int rs = (lm >> 1) & 3;                   // matching read-side XOR
            floatx4 acc[4][4];
            #pragma unroll
            for (int mi = 0; mi < 4; ++mi)
                #pragma unroll
                for (int ni = 0; ni < 4; ++ni) acc[mi][ni] = (floatx4){0.f, 0.f, 0.f, 0.f};
            int d0 = srow * 32 + slot * 8;
            int d1 = (64 + srow) * 32 + slot * 8;
            const size_t ga0 = (size_t)(i0 + srow) * N_ROWS + kb + (xslot << 3);
            const size_t ga1 = (size_t)(i0 + 64 + srow) * N_ROWS + kb + (xslot << 3);
            const size_t gb0 = (size_t)(j0 + srow) * N_ROWS + kb + (xslot << 3);
            const size_t gb1 = (size_t)(j0 + 64 + srow) * N_ROWS + kb + (xslot << 3);
            cp16(zth + ga0, sm.g.Ah[0] + d0);
            cp16(zth + ga1, sm.g.Ah[0] + d1);
            if (!diag) {
                cp16(zth + gb0, sm.g.Bh[0] + d0);
                cp16(zth + gb1, sm.g.Bh[0] + d1);
            }
            __syncthreads();
            for (int s = 0; s < 16; ++s) {
                int cur = s & 1, nxt = cur ^ 1;
                if (s + 1 < 16) {
                    int ks = (s + 1) << 5;
                    cp16(zth + ga0 + ks, sm.g.Ah[nxt] + d0);
                    cp16(zth + ga1 + ks, sm.g.Ah[nxt] + d1);
                    if (!diag) {
                        cp16(zth + gb0 + ks, sm.g.Bh[nxt] + d0);
                        cp16(zth + gb1 + ks, sm.g.Bh[nxt] + d1);
                    }
                }
                const u16* Bhs = diag ? sm.g.Ah[cur] : sm.g.Bh[cur];
                half8 ah[4], bh[4];
                #pragma unroll
                for (int mi = 0; mi < 4; ++mi) {
                    int off = (((w & 1) << 6) + (mi << 4) + lm) * 32 + ((lg ^ rs) << 3);
                    ah[mi] = *(const half8*)&sm.g.Ah[cur][off];
                }
                #pragma unroll
                for (int ni = 0; ni < 4; ++ni) {
                    int off = (((w >> 1) << 6) + (ni << 4) + lm) * 32 + ((lg ^ rs) << 3);
                    bh[ni] = *(const half8*)&Bhs[off];
                }
                #pragma unroll
                for (int mi = 0; mi < 4; ++mi)
                    #pragma unroll
                    for (int ni = 0; ni < 4; ++ni)
                        acc[mi][ni] = __builtin_amdgcn_mfma_f32_16x16x32_f16(ah[mi], bh[ni], acc[mi][ni], 0, 0, 0);
                __syncthreads();
            }
            float* Gb = Gp + ((size_t)u << 14);
            #pragma unroll
            for (int mi = 0; mi < 4; ++mi) {
                int row0 = ((w & 1) << 6) + (mi << 4) + (lg << 2);
                #pragma unroll
                for (int ni = 0; ni < 4; ++ni) {
                    int col = ((w >> 1) << 6) + (ni << 4) + lm;
                    #pragma unroll
                    for (int r = 0; r < 4; ++r)
                        Gb[(size_t)(row0 + r) * 128 + col] = acc[mi][ni][r];
                }
            }
        }
    }
    grid.sync();

    // ---- P3: reduce Gp -> G (mirror lower) + class histogram -----------
    {
        int nth = gdim << 8;
        for (int i = (bx << 8) + t; i < D_DIM * D_DIM; i += nth) {
            int r = i >> 9, c = i & 511;
            int tr = r >> 7, tc = c >> 7, rr = r & 127, cc = c & 127;
            if (tr > tc) { int tmp = tr; tr = tc; tc = tmp; tmp = rr; rr = cc; cc = tmp; }
            int tid = tr * 4 + tc - ((tr * (tr + 1)) >> 1);
            const float* src = Gp + ((size_t)tid << 14) + rr * 128 + cc;
            float s = 0.f;
            #pragma unroll
            for (int p = 0; p < SPLITK; ++p) s += src[(size_t)p * 163840];
            G[i] = s;
        }
        if (bx < 64 && t < 128)
            atomicAdd(&cnt[cls[(bx << 7) + t]], 1);
    }
    grid.sync();

    // ---- P4: prototypes (13 class-groups x 16 col-panels) --------------
    for (int u = bx; u < 208; u += gdim) {
        __syncthreads();
        int g = u >> 4, panel = u & 15;
        for (int idx = t; idx < 8 * 512; idx += 256) {
            int ci = idx >> 9, k = idx & 511;
            int cc = g * 8 + ci;
            sm.d.us[ci][k] = (cc < C_CLS) ? u_arr[(size_t)cc * D_DIM + k] : 0.f;
        }
        __syncthreads();
        int ci = t >> 5, cj = t & 31;
        int c = g * 8 + ci;
        int j = panel * 32 + cj;
        float acc = 0.f;
        #pragma unroll 8
        for (int k = 0; k < D_DIM; ++k)
            acc += sm.d.us[ci][k] * G[(size_t)k * D_DIM + j];
        if (c < C_CLS) {
            int n = cnt[c];
            float s = (n > 0) ? 1.0f / (float)n : 0.0f;
            out[(size_t)c * D_DIM + j] = (v_arr[(size_t)c * D_DIM + j] + acc) * s;
        }
    }
    grid.sync();

    // ---- P5: inter[i,j,:] = proto[j] - proto[i] ------------------------
    {
        float* inter = out + C_CLS * D_DIM;
        for (int u = bx; u < (C_CLS * C_CLS) / 4; u += gdim) {
            int pair = (u << 2) + wid;
            int i = pair / C_CLS;
            int j = pair - i * C_CLS;
            int d = lane << 3;
            float4 pj0 = *(const float4*)&out[j * D_DIM + d];
            float4 pj1 = *(const float4*)&out[j * D_DIM + d + 4];
            float4 pi0 = *(const float4*)&out[i * D_DIM + d];
            float4 pi1 = *(const float4*)&out[i * D_DIM + d + 4];
            float4 r0, r1;
            r0.x = pj0.x - pi0.x; r0.y = pj0.y - pi0.y; r0.z = pj0.z - pi0.z; r0.w = pj0.w - pi0.w;
            r1.x = pj1.x - pi1.x; r1.y = pj1.y - pi1.y; r1.z = pj1.z - pi1.z; r1.w = pj1.w - pi1.w;
            *(float4*)&inter[(size_t)pair * D_DIM + d]     = r0;
            *(float4*)&inter[(size_t)pair * D_DIM + d + 4] = r1;
        }
    }
}

// ======================= fallback multi-kernel path (round-1) ===============
__global__ __launch_bounds__(256) void kA(const float* __restrict__ logits,
        const float* __restrict__ x, float* __restrict__ wv, int* __restrict__ cls,
        float* __restrict__ inv, u16* __restrict__ zth, int* __restrict__ cnt) {
    __shared__ float xs[16 * LDA];
    __shared__ float ns[16];
    __shared__ float sv_s[16];
    int bx = blockIdx.x, t = threadIdx.x;
    if (bx < 1024) {
        int lane = t & 63;
        int row0 = (bx << 3) + ((t >> 6) << 1);
        #pragma unroll
        for (int rr = 0; rr < 2; ++rr) {
            int row = row0 + rr;
            const float* lrow = logits + (size_t)row * C_CLS;
            float v1 = lrow[lane];
            bool has2 = (lane + 64) < C_CLS;
            float v2 = has2 ? lrow[lane + 64] : -INFINITY;
            float m; int idx;
            if (v2 > v1) { m = v2; idx = lane + 64; } else { m = v1; idx = lane; }
            #pragma unroll
            for (int off = 32; off >= 1; off >>= 1) {
                float om = __shfl_down(m, off);
                int   oi = __shfl_down(idx, off);
                if (om > m || (om == m && oi < idx)) { m = om; idx = oi; }
            }
            m = __shfl(m, 0); idx = __shfl(idx, 0);
            float s = expf(v1 - m) + (has2 ? expf(v2 - m) : 0.0f);
            #pragma unroll
            for (int off = 32; off >= 1; off >>= 1) s += __shfl_down(s, off);
            if (lane == 0) { wv[row] = 1.0f / s; cls[row] = idx; atomicAdd(&cnt[idx], 1); }
        }
        return;
    }
    int r0 = (bx - 1024) << 4;
    const float* src = x + (size_t)r0 * D_DIM;
    #pragma unroll
    for (int i = 0; i < 8; ++i) {
        int e = i * 1024 + t * 4;
        int r = e >> 9, c = e & 511;
        *(float4*)&xs[r * LDA + c] = *(const float4*)&src[e];
    }
    __syncthreads();
    {
        int r = t & 15, seg = t >> 4;
        const float* row = &xs[r * LDA + seg * 32];
        float ss = 0.f;
        #pragma unroll
        for (int jj = 0; jj < 32; ++jj) { float v = row[jj]; ss += v * v; }
        ns[r] = 0.f;
        __syncthreads();
        atomicAdd(&ns[r], ss);
    }
    __syncthreads();
    if (t < 16) {
        float iv = 1.0f / fmaxf(sqrtf(ns[t]), 1e-8f);
        inv[r0 + t] = iv;
        sv_s[t] = sqrtf(iv);
    }
    __syncthreads();
    int c = t >> 1, rq = (t & 1) * 8;
    float svl[8];
    #pragma unroll
    for (int ii = 0; ii < 8; ++ii) svl[ii] = sv_s[rq + ii];
    #pragma unroll
    for (int ct = 0; ct < 4; ++ct) {
        int d = ct * 128 + c;
        u16 o[8];
        #pragma unroll
        for (int ii = 0; ii < 8; ++ii)
            o[ii] = f2h(xs[(rq + ii) * LDA + d] * svl[ii]);
        uint4 val = make_uint4((u32)o[0] | ((u32)o[1] << 16),
                               (u32)o[2] | ((u32)o[3] << 16),
                               (u32)o[4] | ((u32)o[5] << 16),
                               (u32)o[6] | ((u32)o[7] << 16));
        *(uint4*)&zth[(size_t)d * N_ROWS + r0 + rq] = val;
    }
}

__global__ __launch_bounds__(256) void kC(const u16* __restrict__ zth,
        const float* __restrict__ x, const float* __restrict__ inv,
        const float* __restrict__ wv, const int* __restrict__ cls,
        float* __restrict__ Gp, float* __restrict__ u_arr, float* __restrict__ v_arr) {
    __shared__ __attribute__((aligned(16))) union {
        struct { u16 Ah[2][128 * 32], Bh[2][128 * 32]; } g;
        struct { float us[4][64], vs[4][64]; } uv;
    } sm;
    int bx = blockIdx.x, t = threadIdx.x;
    if (bx >= 160) {
        int idx = bx - 160;
        int c = idx >> 3, jc = idx & 7;
        int g = t >> 6, lane = t & 63;
        int j = jc * 64 + lane;
        float ua = 0.f, va = 0.f;
        int base = g * 2048;
        for (int b = 0; b < 2048; b += 64) {
            int mb = base + b;
            unsigned long long mask = __ballot(cls[mb + lane] == c);
            while (mask) {
                int bit = __builtin_ctzll(mask);
                mask &= mask - 1;
                int m = mb + bit;
                float wm = wv[m];
                float wi = wm * inv[m];
                float xv = x[(size_t)m * D_DIM + j];
                ua += wi * xv; va += wm * xv;
            }
        }
        sm.uv.us[g][lane] = ua; sm.uv.vs[g][lane] = va;
        __syncthreads();
        if (g == 0) {
            u_arr[(size_t)c * D_DIM + j] = sm.uv.us[0][lane] + sm.uv.us[1][lane] + sm.uv.us[2][lane] + sm.uv.us[3][lane];
            v_arr[(size_t)c * D_DIM + j] = sm.uv.vs[0][lane] + sm.uv.vs[1][lane] + sm.uv.vs[2][lane] + sm.uv.vs[3][lane];
        }
        return;
    }
    int tile = bx % 10;
    int p = bx / 10;
    int ti = tile < 4 ? 0 : (tile < 7 ? 1 : (tile < 9 ? 2 : 3));
    int tj = tile - (ti == 0 ? 0 : (ti == 1 ? 3 : (ti == 2 ? 5 : 6)));
    int i0 = ti << 7, j0 = tj << 7;
    bool diag = (ti == tj);
    int kb = p << 9;
    int w = t >> 6, l = t & 63;
    int srow = t >> 2, slot = t & 3;
    int xslot = slot ^ ((srow >> 1) & 3);
    int lm = l & 15, lg = l >> 4;
    int rs = (lm >> 1) & 3;
    floatx4 acc[4][4];
    #pragma unroll
    for (int mi = 0; mi < 4; ++mi)
        #pragma unroll
        for (int ni = 0; ni < 4; ++ni) acc[mi][ni] = (floatx4){0.f, 0.f, 0.f, 0.f};
    int d0 = srow * 32 + slot * 8;
    int d1 = (64 + srow) * 32 + slot * 8;
    const size_t ga0 = (size_t)(i0 + srow) * N_ROWS + kb + (xslot << 3);
    const size_t ga1 = (size_t)(i0 + 64 + srow) * N_ROWS + kb + (xslot << 3);
    const size_t gb0 = (size_t)(j0 + srow) * N_ROWS + kb + (xslot << 3);
    const size_t gb1 = (size_t)(j0 + 64 + srow) * N_ROWS + kb + (xslot << 3);
    cp16(zth + ga0, sm.g.Ah[0] + d0);
    cp16(zth + ga1, sm.g.Ah[0] + d1);
    if (!diag) { cp16(zth + gb0, sm.g.Bh[0] + d0); cp16(zth + gb1, sm.g.Bh[0] + d1); }
    __syncthreads();
    for (int s = 0; s < 16; ++s) {
        int cur = s & 1, nxt = cur ^ 1;
        if (s + 1 < 16) {
            int ks = (s + 1) << 5;
            cp16(zth + ga0 + ks, sm.g.Ah[nxt] + d0);
            cp16(zth + ga1 + ks, sm.g.Ah[nxt] + d1);
            if (!diag) { cp16(zth + gb0 + ks, sm.g.Bh[nxt] + d0); cp16(zth + gb1 + ks, sm.g.Bh[nxt] + d1); }
        }
        const u16* Bhs = diag ? sm.g.Ah[cur] : sm.g.Bh[cur];
        half8 ah[4], bh[4];
        #pragma unroll
        for (int mi = 0; mi < 4; ++mi) {
            int off = (((w & 1) << 6) + (mi << 4) + lm) * 32 + ((lg ^ rs) << 3);
            ah[mi] = *(const half8*)&sm.g.Ah[cur][off];
        }
        #pragma unroll
        for (int ni = 0; ni < 4; ++ni) {
            int off = (((w >> 1) << 6) + (ni << 4) + lm) * 32 + ((lg ^ rs) << 3);
            bh[ni] = *(const half8*)&Bhs[off];
        }
        #pragma unroll
        for (int mi = 0; mi < 4; ++mi)
            #pragma unroll
            for (int ni = 0; ni < 4; ++ni)
                acc[mi][ni] = __builtin_amdgcn_mfma_f32_16x16x32_f16(ah[mi], bh[ni], acc[mi][ni], 0, 0, 0);
        __syncthreads();
    }
    float* Gb = Gp + ((size_t)bx << 14);
    #pragma unroll
    for (int mi = 0; mi < 4; ++mi) {
        int row0 = ((w & 1) << 6) + (mi << 4) + (lg << 2);
        #pragma unroll
        for (int ni = 0; ni < 4; ++ni) {
            int col = ((w >> 1) << 6) + (ni << 4) + lm;
            #pragma unroll
            for (int r = 0; r < 4; ++r)
                Gb[(size_t)(row0 + r) * 128 + col] = acc[mi][ni][r];
        }
    }
}

__global__ __launch_bounds__(256) void kR(const float* __restrict__ Gp,
                                          float* __restrict__ G) {
    int i = blockIdx.x * 256 + threadIdx.x;
    int r = i >> 9, c = i & 511;
    int tr = r >> 7, tc = c >> 7, rr = r & 127, cc = c & 127;
    if (tr > tc) { int tmp = tr; tr = tc; tc = tmp; tmp = rr; rr = cc; cc = tmp; }
    int tid = tr * 4 + tc - ((tr * (tr + 1)) >> 1);
    const float* src = Gp + ((size_t)tid << 14) + rr * 128 + cc;
    float s = 0.f;
    #pragma unroll
    for (int p = 0; p < SPLITK; ++p) s += src[(size_t)p * 163840];
    G[i] = s;
}

__global__ __launch_bounds__(256) void kD(const float* __restrict__ u_arr,
        const float* __restrict__ v_arr, const int* __restrict__ cnt,
        const float* __restrict__ G, float* __restrict__ out) {
    __shared__ float us[8][512];
    int g = blockIdx.x >> 4;
    int panel = blockIdx.x & 15;
    int t = threadIdx.x;
    for (int idx = t; idx < 8 * 512; idx += 256) {
        int ci = idx >> 9, k = idx & 511;
        int cc = g * 8 + ci;
        us[ci][k] = (cc < C_CLS) ? u_arr[(size_t)cc * D_DIM + k] : 0.f;
    }
    __syncthreads();
    int ci = t >> 5, cj = t & 31;
    int c = g * 8 + ci;
    int j = panel * 32 + cj;
    float acc = 0.f;
    #pragma unroll 8
    for (int k = 0; k < D_DIM; ++k)
        acc += us[ci][k] * G[(size_t)k * D_DIM + j];
    if (c < C_CLS) {
        int n = cnt[c];
        float s = (n > 0) ? 1.0f / (float)n : 0.0f;
        out[(size_t)c * D_DIM + j] = (v_arr[(size_t)c * D_DIM + j] + acc) * s;
    }
}

__global__ __launch_bounds__(256) void kE(const float* __restrict__ proto,
                                          float* __restrict__ inter) {
    int pair = blockIdx.x * 4 + (threadIdx.x >> 6);
    int i = pair / C_CLS;
    int j = pair - i * C_CLS;
    int d = (threadIdx.x & 63) << 3;
    float4 pj0 = *(const float4*)&proto[j * D_DIM + d];
    float4 pj1 = *(const float4*)&proto[j * D_DIM + d + 4];
    float4 pi0 = *(const float4*)&proto[i * D_DIM + d];
    float4 pi1 = *(const float4*)&proto[i * D_DIM + d + 4];
    float4 r0, r1;
    r0.x = pj0.x - pi0.x; r0.y = pj0.y - pi0.y; r0.z = pj0.z - pi0.z; r0.w = pj0.w - pi0.w;
    r1.x = pj1.x - pi1.x; r1.y = pj1.y - pi1.y; r1.z = pj1.z - pi1.z; r1.w = pj1.w - pi1.w;
    *(float4*)&inter[(size_t)pair * D_DIM + d]     = r0;
    *(float4*)&inter[(size_t)pair * D_DIM + d + 4] = r1;
}

extern "C" void kernel_launch(void* const* d_in, const int* in_sizes, int n_in,
                              void* d_out, int out_size, void* d_ws, size_t ws_size,
                              hipStream_t stream) {
    const float* x      = (const float*)d_in[0];   // [8192, 512]
    const float* logits = (const float*)d_in[1];   // [8192, 100]
    float* out = (float*)d_out;
    float* ws  = (float*)d_ws;
    float* G     = ws + WS_G;
    float* Gp    = ws + WS_GP;
    float* inv   = ws + WS_INV;
    float* wv    = ws + WS_WV;
    int*   cls   = (int*)(ws + WS_CLS);
    int*   cnt   = (int*)(ws + WS_CNT);
    float* u_arr = ws + WS_U;
    float* v_arr = ws + WS_V;
    u16* zth = (u16*)(ws + WS_ZTH);

    static int nblk = 0;
    static int coop_ok = 1;
    if (nblk == 0) {
        int bpc = 0;
        hipError_t e = hipOccupancyMaxActiveBlocksPerMultiprocessor(&bpc, kFused, 256, 0);
        if (e != hipSuccess || bpc < 1) { coop_ok = 0; bpc = 1; }
        if (bpc > 8) bpc = 8;
        nblk = bpc * 256;
    }

    if (coop_ok) {
        void* args[] = { (void*)&logits, (void*)&x, (void*)&wv, (void*)&cls,
                         (void*)&inv, (void*)&zth, (void*)&cnt, (void*)&Gp,
                         (void*)&G, (void*)&u_arr, (void*)&v_arr, (void*)&out };
        hipError_t e = hipLaunchCooperativeKernel((const void*)kFused, dim3(nblk),
                                                  dim3(256), args, 0, stream);
        if (e == hipSuccess) return;
        coop_ok = 0;   // fall through to multi-kernel path
    }

    hipMemsetAsync(cnt, 0, 128 * sizeof(int), stream);
    kA<<<1536, 256, 0, stream>>>(logits, x, wv, cls, inv, zth, cnt);
    kC<<<960, 256, 0, stream>>>(zth, x, inv, wv, cls, Gp, u_arr, v_arr);
    kR<<<1024, 256, 0, stream>>>(Gp, G);
    kD<<<208, 256, 0, stream>>>(u_arr, v_arr, cnt, G, out);
    kE<<<C_CLS * C_CLS / 4, 256, 0, stream>>>(out, out + C_CLS * D_DIM);
}

// Round 3
// 179.319 us; speedup vs baseline: 1.7257x; 1.7257x over previous
//
#include <hip/hip_runtime.h>
#include <math.h>

#define N_ROWS 8192
#define D_DIM  512
#define C_CLS  100
#define SPLITK 32

typedef unsigned short u16;
typedef unsigned int u32;
typedef __attribute__((ext_vector_type(8))) _Float16 half8;
typedef __attribute__((ext_vector_type(4))) float floatx4;

// ---------------- ws layout (float offsets) ----------------
#define WS_G      0              // 512*512 fp32
#define WS_GP     262144         // 32*10*16384 fp32 splitK partials
#define WS_INV    5505024        // 8192
#define WS_WV     5513216        // 8192
#define WS_CLS    5521408        // 8192 (int)
#define WS_CNT    5529600        // 128 (int)
#define WS_U      5538048        // 100*512
#define WS_V      5589248        // 100*512
#define WS_ZTH    5640448        // 512*8192 fp16

typedef const __attribute__((address_space(1))) u32* gp32;
typedef __attribute__((address_space(3))) u32* lp32;
__device__ __forceinline__ void cp16(const u16* g, u16* l) {
    __builtin_amdgcn_global_load_lds((gp32)g, (lp32)l, 16, 0, 0);
}

__device__ __forceinline__ u16 f2h(float v) {
    _Float16 h = (_Float16)v;
    return *(u16*)&h;
}

// ===== kA: bx<1024 softmax (8 rows) | [1024,1152) 64-row norm+cvt+transpose =====
// Transpose uses 64-row stripes so every zth store is a full 64B line
// (lane-pair writes 128B contiguous along m). 16-row version wrote 32B
// half-lines at 16KB stride -> partial-line RMW amplification.
__global__ __launch_bounds__(256) void kA(const float* __restrict__ logits,
        const float* __restrict__ x, float* __restrict__ wv, int* __restrict__ cls,
        float* __restrict__ inv, u16* __restrict__ zth) {
    __shared__ float xs[64 * 132];      // 33.8 KB: [64 m][128 d] fp32 panel
    __shared__ float sv_s[64];
    int bx = blockIdx.x, t = threadIdx.x;
    int lane = t & 63, w = t >> 6;
    if (bx < 1024) {
        int row0 = (bx << 3) + (w << 1);
        #pragma unroll
        for (int rr = 0; rr < 2; ++rr) {
            int row = row0 + rr;
            const float* lrow = logits + (size_t)row * C_CLS;
            float v1 = lrow[lane];
            bool has2 = (lane + 64) < C_CLS;
            float v2 = has2 ? lrow[lane + 64] : -INFINITY;
            float m; int idx;
            if (v2 > v1) { m = v2; idx = lane + 64; } else { m = v1; idx = lane; }
            #pragma unroll
            for (int off = 32; off >= 1; off >>= 1) {
                float om = __shfl_down(m, off);
                int   oi = __shfl_down(idx, off);
                if (om > m || (om == m && oi < idx)) { m = om; idx = oi; }
            }
            m = __shfl(m, 0); idx = __shfl(idx, 0);
            float s = expf(v1 - m) + (has2 ? expf(v2 - m) : 0.0f);
            #pragma unroll
            for (int off = 32; off >= 1; off >>= 1) s += __shfl_down(s, off);
            if (lane == 0) { wv[row] = 1.0f / s; cls[row] = idx; }
        }
        return;
    }
    int r0 = (bx - 1024) << 6;          // 64-row stripe
    // ---- norms: each wave reduces 16 rows straight from global ----
    for (int rr = 0; rr < 16; ++rr) {
        int rl = (w << 4) + rr;
        const float* row = x + (size_t)(r0 + rl) * D_DIM + (lane << 3);
        float4 a = *(const float4*)row;
        float4 b = *(const float4*)(row + 4);
        float ss = a.x * a.x + a.y * a.y + a.z * a.z + a.w * a.w
                 + b.x * b.x + b.y * b.y + b.z * b.z + b.w * b.w;
        #pragma unroll
        for (int off = 32; off >= 1; off >>= 1) ss += __shfl_down(ss, off);
        if (lane == 0) {
            float iv = 1.0f / fmaxf(sqrtf(ss), 1e-8f);
            inv[r0 + rl] = iv;
            sv_s[rl] = sqrtf(iv);
        }
    }
    __syncthreads();
    // ---- 4 d-panels: stage [64m][128d], write zth[d][m] full-line ----
    for (int it = 0; it < 4; ++it) {
        int dB = it << 7;
        #pragma unroll
        for (int i = 0; i < 8; ++i) {
            int e = (i << 10) + (t << 2);
            int m = e >> 7, dl = e & 127;
            *(float4*)&xs[m * 132 + dl] =
                *(const float4*)&x[(size_t)(r0 + m) * D_DIM + dB + dl];
        }
        __syncthreads();
        int dp = t >> 1, h = t & 1;     // lane-pair: same d, m-halves 0-31/32-63
        u16* dst = zth + (size_t)(dB + dp) * N_ROWS + r0 + (h << 5);
        #pragma unroll
        for (int q = 0; q < 4; ++q) {
            u16 o[8];
            #pragma unroll
            for (int ii = 0; ii < 8; ++ii) {
                int m = (h << 5) + (q << 3) + ii;
                o[ii] = f2h(xs[m * 132 + dp] * sv_s[m]);
            }
            uint4 val = make_uint4((u32)o[0] | ((u32)o[1] << 16),
                                   (u32)o[2] | ((u32)o[3] << 16),
                                   (u32)o[4] | ((u32)o[5] << 16),
                                   (u32)o[6] | ((u32)o[7] << 16));
            *(uint4*)&dst[q << 3] = val;
        }
        __syncthreads();
    }
}

// ===== kC: blocks 0..319 fp16 GEMM (splitK=32, dbuf + XOR-swizzle);
//           blocks 320..1119 uv ballot-scan + popcount cnt (no kB/memset) ====
__global__ __launch_bounds__(256) void kC(const u16* __restrict__ zth,
        const float* __restrict__ x, const float* __restrict__ inv,
        const float* __restrict__ wv, const int* __restrict__ cls,
        float* __restrict__ Gp, float* __restrict__ u_arr, float* __restrict__ v_arr,
        int* __restrict__ cnt) {
    __shared__ __attribute__((aligned(16))) union {
        struct { u16 Ah[2][128 * 32], Bh[2][128 * 32]; } g;   // 32 KB dbuf
        struct { float us[4][64], vs[4][64]; int cnts[4]; } uv;
    } sm;
    int bx = blockIdx.x, t = threadIdx.x;
    if (bx >= 320) {
        int idx = bx - 320;
        int c = idx >> 3, jc = idx & 7;
        int g = t >> 6, lane = t & 63;
        int j = jc * 64 + lane;
        float ua = 0.f, va = 0.f;
        int pc = 0;
        int base = g * 2048;
        for (int b = 0; b < 2048; b += 64) {
            int mb = base + b;
            unsigned long long mask = __ballot(cls[mb + lane] == c);
            pc += __popcll(mask);
            while (mask) {
                int bit = __builtin_ctzll(mask);
                mask &= mask - 1;
                int m = mb + bit;               // wave-uniform row index
                float wm = wv[m];
                float wi = wm * inv[m];
                float xv = x[(size_t)m * D_DIM + j];
                ua += wi * xv; va += wm * xv;
            }
        }
        sm.uv.us[g][lane] = ua; sm.uv.vs[g][lane] = va;
        if (lane == 0) sm.uv.cnts[g] = pc;
        __syncthreads();
        if (g == 0) {
            u_arr[(size_t)c * D_DIM + j] = sm.uv.us[0][lane] + sm.uv.us[1][lane] + sm.uv.us[2][lane] + sm.uv.us[3][lane];
            v_arr[(size_t)c * D_DIM + j] = sm.uv.vs[0][lane] + sm.uv.vs[1][lane] + sm.uv.vs[2][lane] + sm.uv.vs[3][lane];
            if (lane == 0 && jc == 0)
                cnt[c] = sm.uv.cnts[0] + sm.uv.cnts[1] + sm.uv.cnts[2] + sm.uv.cnts[3];
        }
        return;
    }
    int tile = bx % 10;
    int p = bx / 10;                    // 0..31, K-chunk of 256
    int ti = tile < 4 ? 0 : (tile < 7 ? 1 : (tile < 9 ? 2 : 3));
    int tj = tile - (ti == 0 ? 0 : (ti == 1 ? 3 : (ti == 2 ? 5 : 6)));
    int i0 = ti << 7, j0 = tj << 7;
    bool diag = (ti == tj);
    int kb = p << 8;
    int w = t >> 6, l = t & 63;
    int srow = t >> 2, slot = t & 3;
    // rule 21: linear LDS dest, XOR-swizzled GLOBAL source, same XOR on read
    int xslot = slot ^ ((srow >> 1) & 3);
    int lm = l & 15, lg = l >> 4;
    int rs = (lm >> 1) & 3;
    floatx4 acc[4][4];
    #pragma unroll
    for (int mi = 0; mi < 4; ++mi)
        #pragma unroll
        for (int ni = 0; ni < 4; ++ni) acc[mi][ni] = (floatx4){0.f, 0.f, 0.f, 0.f};
    int d0 = srow * 32 + slot * 8;
    int d1 = (64 + srow) * 32 + slot * 8;
    const size_t ga0 = (size_t)(i0 + srow) * N_ROWS + kb + (xslot << 3);
    const size_t ga1 = (size_t)(i0 + 64 + srow) * N_ROWS + kb + (xslot << 3);
    const size_t gb0 = (size_t)(j0 + srow) * N_ROWS + kb + (xslot << 3);
    const size_t gb1 = (size_t)(j0 + 64 + srow) * N_ROWS + kb + (xslot << 3);
    cp16(zth + ga0, sm.g.Ah[0] + d0);
    cp16(zth + ga1, sm.g.Ah[0] + d1);
    if (!diag) {
        cp16(zth + gb0, sm.g.Bh[0] + d0);
        cp16(zth + gb1, sm.g.Bh[0] + d1);
    }
    __syncthreads();
    for (int s = 0; s < 8; ++s) {
        int cur = s & 1, nxt = cur ^ 1;
        if (s + 1 < 8) {
            int ks = (s + 1) << 5;
            cp16(zth + ga0 + ks, sm.g.Ah[nxt] + d0);
            cp16(zth + ga1 + ks, sm.g.Ah[nxt] + d1);
            if (!diag) {
                cp16(zth + gb0 + ks, sm.g.Bh[nxt] + d0);
                cp16(zth + gb1 + ks, sm.g.Bh[nxt] + d1);
            }
        }
        const u16* Bhs = diag ? sm.g.Ah[cur] : sm.g.Bh[cur];
        half8 ah[4], bh[4];
        #pragma unroll
        for (int mi = 0; mi < 4; ++mi) {
            int off = (((w & 1) << 6) + (mi << 4) + lm) * 32 + ((lg ^ rs) << 3);
            ah[mi] = *(const half8*)&sm.g.Ah[cur][off];
        }
        #pragma unroll
        for (int ni = 0; ni < 4; ++ni) {
            int off = (((w >> 1) << 6) + (ni << 4) + lm) * 32 + ((lg ^ rs) << 3);
            bh[ni] = *(const half8*)&Bhs[off];
        }
        #pragma unroll
        for (int mi = 0; mi < 4; ++mi)
            #pragma unroll
            for (int ni = 0; ni < 4; ++ni)
                acc[mi][ni] = __builtin_amdgcn_mfma_f32_16x16x32_f16(ah[mi], bh[ni], acc[mi][ni], 0, 0, 0);
        __syncthreads();
    }
    float* Gb = Gp + ((size_t)bx << 14);
    #pragma unroll
    for (int mi = 0; mi < 4; ++mi) {
        int row0 = ((w & 1) << 6) + (mi << 4) + (lg << 2);
        #pragma unroll
        for (int ni = 0; ni < 4; ++ni) {
            int col = ((w >> 1) << 6) + (ni << 4) + lm;
            #pragma unroll
            for (int r = 0; r < 4; ++r)
                Gb[(size_t)(row0 + r) * 128 + col] = acc[mi][ni][r];
        }
    }
}

// ===== kR: G[r][c] = sum_p Gp[p][uppertile(r,c)] (mirror lower) =====
__global__ __launch_bounds__(256) void kR(const float* __restrict__ Gp,
                                          float* __restrict__ G) {
    int i = blockIdx.x * 256 + threadIdx.x;      // 0..262143
    int r = i >> 9, c = i & 511;
    int tr = r >> 7, tc = c >> 7, rr = r & 127, cc = c & 127;
    if (tr > tc) { int tmp = tr; tr = tc; tc = tmp; tmp = rr; rr = cc; cc = tmp; }
    int tid = tr * 4 + tc - ((tr * (tr + 1)) >> 1);
    const float* src = Gp + ((size_t)tid << 14) + rr * 128 + cc;
    float s = 0.f;
    #pragma unroll
    for (int p = 0; p < SPLITK; ++p) s += src[(size_t)p * 163840];
    G[i] = s;
}

// ===== kD: protos, tiled for G-reuse: 13 class-groups x 16 col-panels =====
__global__ __launch_bounds__(256) void kD(const float* __restrict__ u_arr,
        const float* __restrict__ v_arr, const int* __restrict__ cnt,
        const float* __restrict__ G, float* __restrict__ out) {
    __shared__ float us[8][512];
    int g = blockIdx.x >> 4;            // 0..12
    int panel = blockIdx.x & 15;        // 0..15
    int t = threadIdx.x;
    for (int idx = t; idx < 8 * 512; idx += 256) {
        int ci = idx >> 9, k = idx & 511;
        int cc = g * 8 + ci;
        us[ci][k] = (cc < C_CLS) ? u_arr[(size_t)cc * D_DIM + k] : 0.f;
    }
    __syncthreads();
    int ci = t >> 5, cj = t & 31;
    int c = g * 8 + ci;
    int j = panel * 32 + cj;
    float acc = 0.f;
    #pragma unroll 8
    for (int k = 0; k < D_DIM; ++k)
        acc += us[ci][k] * G[(size_t)k * D_DIM + j];
    if (c < C_CLS) {
        int n = cnt[c];
        float s = (n > 0) ? 1.0f / (float)n : 0.0f;
        out[(size_t)c * D_DIM + j] = (v_arr[(size_t)c * D_DIM + j] + acc) * s;
    }
}

// ===== kE: inter[i,j,:] = proto[j] - proto[i]; 4 pairs/block =====
__global__ __launch_bounds__(256) void kE(const float* __restrict__ proto,
                                          float* __restrict__ inter) {
    int pair = blockIdx.x * 4 + (threadIdx.x >> 6);
    int i = pair / C_CLS;
    int j = pair - i * C_CLS;
    int d = (threadIdx.x & 63) << 3;
    float4 pj0 = *(const float4*)&proto[j * D_DIM + d];
    float4 pj1 = *(const float4*)&proto[j * D_DIM + d + 4];
    float4 pi0 = *(const float4*)&proto[i * D_DIM + d];
    float4 pi1 = *(const float4*)&proto[i * D_DIM + d + 4];
    float4 r0, r1;
    r0.x = pj0.x - pi0.x; r0.y = pj0.y - pi0.y; r0.z = pj0.z - pi0.z; r0.w = pj0.w - pi0.w;
    r1.x = pj1.x - pi1.x; r1.y = pj1.y - pi1.y; r1.z = pj1.z - pi1.z; r1.w = pj1.w - pi1.w;
    *(float4*)&inter[(size_t)pair * D_DIM + d]     = r0;
    *(float4*)&inter[(size_t)pair * D_DIM + d + 4] = r1;
}

extern "C" void kernel_launch(void* const* d_in, const int* in_sizes, int n_in,
                              void* d_out, int out_size, void* d_ws, size_t ws_size,
                              hipStream_t stream) {
    const float* x      = (const float*)d_in[0];   // [8192, 512]
    const float* logits = (const float*)d_in[1];   // [8192, 100]
    float* out = (float*)d_out;
    float* ws  = (float*)d_ws;
    float* G     = ws + WS_G;
    float* Gp    = ws + WS_GP;
    float* inv   = ws + WS_INV;
    float* wv    = ws + WS_WV;
    int*   cls   = (int*)(ws + WS_CLS);
    int*   cnt   = (int*)(ws + WS_CNT);
    float* u_arr = ws + WS_U;
    float* v_arr = ws + WS_V;
    u16* zth = (u16*)(ws + WS_ZTH);

    kA<<<1152, 256, 0, stream>>>(logits, x, wv, cls, inv, zth);
    kC<<<1120, 256, 0, stream>>>(zth, x, inv, wv, cls, Gp, u_arr, v_arr, cnt);
    kR<<<1024, 256, 0, stream>>>(Gp, G);
    kD<<<208, 256, 0, stream>>>(u_arr, v_arr, cnt, G, out);
    kE<<<C_CLS * C_CLS / 4, 256, 0, stream>>>(out, out + C_CLS * D_DIM);
}

// Round 5
// 166.632 us; speedup vs baseline: 1.8570x; 1.0761x over previous
//
#include <hip/hip_runtime.h>
#include <math.h>

#define N_ROWS 8192
#define D_DIM  512
#define C_CLS  100
#define SPLITK 32

typedef unsigned short u16;
typedef unsigned int u32;
typedef __attribute__((ext_vector_type(8))) _Float16 half8;
typedef __attribute__((ext_vector_type(4))) float floatx4;

// ---------------- ws layout (float offsets) ----------------
#define WS_G      0              // 512*512 fp32
#define WS_GP     262144         // 32*10*16384 fp32 splitK partials (L2/L3-resident)
#define WS_INV    5505024        // 8192
#define WS_WV     5513216        // 8192
#define WS_CLS    5521408        // 8192 (int)
#define WS_CNT    5529600        // 128 (int)
#define WS_U      5538048        // 100*512
#define WS_V      5589248        // 100*512
#define WS_ZTH    5640448        // 512*8192 fp16

#define LDA 517                  // kA LDS stride

typedef const __attribute__((address_space(1))) u32* gp32;
typedef __attribute__((address_space(3))) u32* lp32;
__device__ __forceinline__ void cp16(const u16* g, u16* l) {
    __builtin_amdgcn_global_load_lds((gp32)g, (lp32)l, 16, 0, 0);
}

__device__ __forceinline__ u16 f2h(float v) {
    _Float16 h = (_Float16)v;
    return *(u16*)&h;
}

// ===== kA: round-0 form (best measured). bx<1024 softmax (8 rows);
//           [1024,1536) 16-row stripe: single x read, LDS norms, transpose ====
__global__ __launch_bounds__(256) void kA(const float* __restrict__ logits,
        const float* __restrict__ x, float* __restrict__ wv, int* __restrict__ cls,
        float* __restrict__ inv, u16* __restrict__ zth) {
    __shared__ float xs[16 * LDA];      // 33 KB fp32 stripe (16 rows)
    __shared__ float ns[4][16];
    __shared__ float sv_s[16];
    int bx = blockIdx.x, t = threadIdx.x;
    if (bx < 1024) {
        int lane = t & 63;
        int row0 = (bx << 3) + ((t >> 6) << 1);
        #pragma unroll
        for (int rr = 0; rr < 2; ++rr) {
            int row = row0 + rr;
            const float* lrow = logits + (size_t)row * C_CLS;
            float v1 = lrow[lane];
            bool has2 = (lane + 64) < C_CLS;
            float v2 = has2 ? lrow[lane + 64] : -INFINITY;
            float m; int idx;
            if (v2 > v1) { m = v2; idx = lane + 64; } else { m = v1; idx = lane; }
            #pragma unroll
            for (int off = 32; off >= 1; off >>= 1) {
                float om = __shfl_down(m, off);
                int   oi = __shfl_down(idx, off);
                if (om > m || (om == m && oi < idx)) { m = om; idx = oi; }
            }
            m = __shfl(m, 0);
            idx = __shfl(idx, 0);
            float s = expf(v1 - m) + (has2 ? expf(v2 - m) : 0.0f);
            #pragma unroll
            for (int off = 32; off >= 1; off >>= 1) s += __shfl_down(s, off);
            if (lane == 0) {
                wv[row] = 1.0f / s;
                cls[row] = idx;
            }
        }
        return;
    }
    int r0 = (bx - 1024) << 4;
    const float* src = x + (size_t)r0 * D_DIM;
    #pragma unroll
    for (int i = 0; i < 8; ++i) {
        int e = i * 1024 + t * 4;
        int r = e >> 9, c = e & 511;
        *(float4*)&xs[r * LDA + c] = *(const float4*)&src[e];
    }
    __syncthreads();
    {
        int r = t & 15, seg = t >> 4;
        const float* row = &xs[r * LDA + seg * 32];
        float ss = 0.f;
        #pragma unroll
        for (int jj = 0; jj < 32; ++jj) { float v = row[jj]; ss += v * v; }
        ns[0][r] = 0.f;
        __syncthreads();
        atomicAdd(&ns[0][r], ss);
    }
    __syncthreads();
    if (t < 16) {
        float iv = 1.0f / fmaxf(sqrtf(ns[0][t]), 1e-8f);
        inv[r0 + t] = iv;
        sv_s[t] = sqrtf(iv);
    }
    __syncthreads();
    int c = t >> 1, rq = (t & 1) * 8;
    float svl[8];
    #pragma unroll
    for (int ii = 0; ii < 8; ++ii) svl[ii] = sv_s[rq + ii];
    #pragma unroll
    for (int ct = 0; ct < 4; ++ct) {
        int d = ct * 128 + c;
        u16 o[8];
        #pragma unroll
        for (int ii = 0; ii < 8; ++ii)
            o[ii] = f2h(xs[(rq + ii) * LDA + d] * svl[ii]);
        uint4 val = make_uint4((u32)o[0] | ((u32)o[1] << 16),
                               (u32)o[2] | ((u32)o[3] << 16),
                               (u32)o[4] | ((u32)o[5] << 16),
                               (u32)o[6] | ((u32)o[7] << 16));
        *(uint4*)&zth[(size_t)d * N_ROWS + r0 + rq] = val;
    }
}

// ===== kC: blocks 0..319 fp16 GEMM (splitK=32, K-chunk 256 = 8 steps, dbuf,
//           XOR-swizzle); blocks 320..1119 uv ballot-scan + popcount cnt =====
__global__ __launch_bounds__(256) void kC(const u16* __restrict__ zth,
        const float* __restrict__ x, const float* __restrict__ inv,
        const float* __restrict__ wv, const int* __restrict__ cls,
        float* __restrict__ Gp, float* __restrict__ u_arr, float* __restrict__ v_arr,
        int* __restrict__ cnt) {
    __shared__ __attribute__((aligned(16))) union {
        struct { u16 Ah[2][128 * 32], Bh[2][128 * 32]; } g;   // 32 KB dbuf
        struct { float us[4][64], vs[4][64]; int cnts[4]; } uv;
    } sm;
    int bx = blockIdx.x, t = threadIdx.x;
    if (bx >= 320) {
        int idx = bx - 320;
        int c = idx >> 3, jc = idx & 7;
        int g = t >> 6, lane = t & 63;
        int j = jc * 64 + lane;
        float ua = 0.f, va = 0.f;
        int pc = 0;
        int base = g * 2048;
        for (int b = 0; b < 2048; b += 64) {
            int mb = base + b;
            unsigned long long mask = __ballot(cls[mb + lane] == c);
            pc += __popcll(mask);
            while (mask) {
                int bit = __builtin_ctzll(mask);
                mask &= mask - 1;
                int m = mb + bit;               // wave-uniform row index
                float wm = wv[m];
                float wi = wm * inv[m];
                float xv = x[(size_t)m * D_DIM + j];
                ua += wi * xv; va += wm * xv;
            }
        }
        sm.uv.us[g][lane] = ua; sm.uv.vs[g][lane] = va;
        if (lane == 0) sm.uv.cnts[g] = pc;
        __syncthreads();
        if (g == 0) {
            u_arr[(size_t)c * D_DIM + j] = sm.uv.us[0][lane] + sm.uv.us[1][lane] + sm.uv.us[2][lane] + sm.uv.us[3][lane];
            v_arr[(size_t)c * D_DIM + j] = sm.uv.vs[0][lane] + sm.uv.vs[1][lane] + sm.uv.vs[2][lane] + sm.uv.vs[3][lane];
            if (lane == 0 && jc == 0)
                cnt[c] = sm.uv.cnts[0] + sm.uv.cnts[1] + sm.uv.cnts[2] + sm.uv.cnts[3];
        }
        return;
    }
    int tile = bx % 10;
    int p = bx / 10;                    // 0..31, K-chunk of 256
    int ti = tile < 4 ? 0 : (tile < 7 ? 1 : (tile < 9 ? 2 : 3));
    int tj = tile - (ti == 0 ? 0 : (ti == 1 ? 3 : (ti == 2 ? 5 : 6)));
    int i0 = ti << 7, j0 = tj << 7;
    bool diag = (ti == tj);
    int kb = p << 8;                    // chunk 256 = 8 steps x 32 halfs
    int w = t >> 6, l = t & 63;
    int srow = t >> 2, slot = t & 3;
    // rule 21: linear LDS dest, XOR-swizzled GLOBAL source, same XOR on read
    int xslot = slot ^ ((srow >> 1) & 3);
    int lm = l & 15, lg = l >> 4;
    int rs = (lm >> 1) & 3;
    floatx4 acc[4][4];
    #pragma unroll
    for (int mi = 0; mi < 4; ++mi)
        #pragma unroll
        for (int ni = 0; ni < 4; ++ni) acc[mi][ni] = (floatx4){0.f, 0.f, 0.f, 0.f};
    int d0 = srow * 32 + slot * 8;
    int d1 = (64 + srow) * 32 + slot * 8;
    const size_t ga0 = (size_t)(i0 + srow) * N_ROWS + kb + (xslot << 3);
    const size_t ga1 = (size_t)(i0 + 64 + srow) * N_ROWS + kb + (xslot << 3);
    const size_t gb0 = (size_t)(j0 + srow) * N_ROWS + kb + (xslot << 3);
    const size_t gb1 = (size_t)(j0 + 64 + srow) * N_ROWS + kb + (xslot << 3);
    cp16(zth + ga0, sm.g.Ah[0] + d0);
    cp16(zth + ga1, sm.g.Ah[0] + d1);
    if (!diag) {
        cp16(zth + gb0, sm.g.Bh[0] + d0);
        cp16(zth + gb1, sm.g.Bh[0] + d1);
    }
    __syncthreads();
    for (int s = 0; s < 8; ++s) {
        int cur = s & 1, nxt = cur ^ 1;
        if (s + 1 < 8) {
            int ks = (s + 1) << 5;
            cp16(zth + ga0 + ks, sm.g.Ah[nxt] + d0);
            cp16(zth + ga1 + ks, sm.g.Ah[nxt] + d1);
            if (!diag) {
                cp16(zth + gb0 + ks, sm.g.Bh[nxt] + d0);
                cp16(zth + gb1 + ks, sm.g.Bh[nxt] + d1);
            }
        }
        const u16* Bhs = diag ? sm.g.Ah[cur] : sm.g.Bh[cur];
        half8 ah[4], bh[4];
        #pragma unroll
        for (int mi = 0; mi < 4; ++mi) {
            int off = (((w & 1) << 6) + (mi << 4) + lm) * 32 + ((lg ^ rs) << 3);
            ah[mi] = *(const half8*)&sm.g.Ah[cur][off];
        }
        #pragma unroll
        for (int ni = 0; ni < 4; ++ni) {
            int off = (((w >> 1) << 6) + (ni << 4) + lm) * 32 + ((lg ^ rs) << 3);
            bh[ni] = *(const half8*)&Bhs[off];
        }
        #pragma unroll
        for (int mi = 0; mi < 4; ++mi)
            #pragma unroll
            for (int ni = 0; ni < 4; ++ni)
                acc[mi][ni] = __builtin_amdgcn_mfma_f32_16x16x32_f16(ah[mi], bh[ni], acc[mi][ni], 0, 0, 0);
        __syncthreads();
    }
    float* Gb = Gp + ((size_t)bx << 14);
    #pragma unroll
    for (int mi = 0; mi < 4; ++mi) {
        int row0 = ((w & 1) << 6) + (mi << 4) + (lg << 2);
        #pragma unroll
        for (int ni = 0; ni < 4; ++ni) {
            int col = ((w >> 1) << 6) + (ni << 4) + lm;
            #pragma unroll
            for (int r = 0; r < 4; ++r)
                Gb[(size_t)(row0 + r) * 128 + col] = acc[mi][ni][r];
        }
    }
}

// ===== kR: G[r][c] = sum_p Gp[p][uppertile(r,c)] (mirror lower), splitK=32 ==
__global__ __launch_bounds__(256) void kR(const float* __restrict__ Gp,
                                          float* __restrict__ G) {
    int i = blockIdx.x * 256 + threadIdx.x;      // 0..262143
    int r = i >> 9, c = i & 511;
    int tr = r >> 7, tc = c >> 7, rr = r & 127, cc = c & 127;
    if (tr > tc) { int tmp = tr; tr = tc; tc = tmp; tmp = rr; rr = cc; cc = tmp; }
    int tid = tr * 4 + tc - ((tr * (tr + 1)) >> 1);
    const float* src = Gp + ((size_t)tid << 14) + rr * 128 + cc;
    float s = 0.f;
    #pragma unroll
    for (int p = 0; p < SPLITK; ++p) s += src[(size_t)p * 163840];
    G[i] = s;
}

// ===== kD: protos, tiled for G-reuse: 13 class-groups x 16 col-panels =====
__global__ __launch_bounds__(256) void kD(const float* __restrict__ u_arr,
        const float* __restrict__ v_arr, const int* __restrict__ cnt,
        const float* __restrict__ G, float* __restrict__ out) {
    __shared__ float us[8][512];
    int g = blockIdx.x >> 4;            // 0..12
    int panel = blockIdx.x & 15;        // 0..15
    int t = threadIdx.x;
    for (int idx = t; idx < 8 * 512; idx += 256) {
        int ci = idx >> 9, k = idx & 511;
        int cc = g * 8 + ci;
        us[ci][k] = (cc < C_CLS) ? u_arr[(size_t)cc * D_DIM + k] : 0.f;
    }
    __syncthreads();
    int ci = t >> 5, cj = t & 31;
    int c = g * 8 + ci;
    int j = panel * 32 + cj;
    float acc = 0.f;
    #pragma unroll 8
    for (int k = 0; k < D_DIM; ++k)
        acc += us[ci][k] * G[(size_t)k * D_DIM + j];
    if (c < C_CLS) {
        int n = cnt[c];
        float s = (n > 0) ? 1.0f / (float)n : 0.0f;
        out[(size_t)c * D_DIM + j] = (v_arr[(size_t)c * D_DIM + j] + acc) * s;
    }
}

// ===== kE: inter[i,j,:] = proto[j] - proto[i]; 4 pairs/block =====
__global__ __launch_bounds__(256) void kE(const float* __restrict__ proto,
                                          float* __restrict__ inter) {
    int pair = blockIdx.x * 4 + (threadIdx.x >> 6);
    int i = pair / C_CLS;
    int j = pair - i * C_CLS;
    int d = (threadIdx.x & 63) << 3;
    float4 pj0 = *(const float4*)&proto[j * D_DIM + d];
    float4 pj1 = *(const float4*)&proto[j * D_DIM + d + 4];
    float4 pi0 = *(const float4*)&proto[i * D_DIM + d];
    float4 pi1 = *(const float4*)&proto[i * D_DIM + d + 4];
    float4 r0, r1;
    r0.x = pj0.x - pi0.x; r0.y = pj0.y - pi0.y; r0.z = pj0.z - pi0.z; r0.w = pj0.w - pi0.w;
    r1.x = pj1.x - pi1.x; r1.y = pj1.y - pi1.y; r1.z = pj1.z - pi1.z; r1.w = pj1.w - pi1.w;
    *(float4*)&inter[(size_t)pair * D_DIM + d]     = r0;
    *(float4*)&inter[(size_t)pair * D_DIM + d + 4] = r1;
}

extern "C" void kernel_launch(void* const* d_in, const int* in_sizes, int n_in,
                              void* d_out, int out_size, void* d_ws, size_t ws_size,
                              hipStream_t stream) {
    const float* x      = (const float*)d_in[0];   // [8192, 512]
    const float* logits = (const float*)d_in[1];   // [8192, 100]
    float* out = (float*)d_out;
    float* ws  = (float*)d_ws;
    float* G     = ws + WS_G;
    float* Gp    = ws + WS_GP;
    float* inv   = ws + WS_INV;
    float* wv    = ws + WS_WV;
    int*   cls   = (int*)(ws + WS_CLS);
    int*   cnt   = (int*)(ws + WS_CNT);
    float* u_arr = ws + WS_U;
    float* v_arr = ws + WS_V;
    u16* zth = (u16*)(ws + WS_ZTH);

    kA<<<1536, 256, 0, stream>>>(logits, x, wv, cls, inv, zth);
    kC<<<1120, 256, 0, stream>>>(zth, x, inv, wv, cls, Gp, u_arr, v_arr, cnt);
    kR<<<1024, 256, 0, stream>>>(Gp, G);
    kD<<<208, 256, 0, stream>>>(u_arr, v_arr, cnt, G, out);
    kE<<<C_CLS * C_CLS / 4, 256, 0, stream>>>(out, out + C_CLS * D_DIM);
}